// Round 3
// baseline (541.801 us; speedup 1.0000x reference)
//
#include <hip/hip_runtime.h>
#include <stdint.h>

// SparseLinear: out[m][n] = sum_k x[m][k] * W[n][k] * mask[n][k]
// M = B*S = 8192, N = 4096, K = 4096, fp32 in/out, bf16-tolerance check.
//
// R5 = R4 resubmission (R4 bench died to container/infra failure; kernel
// re-audited: uniform barrier counts, bijective swizzles, vmcnt>=0 waits,
// 160 KiB LDS is a known-launchable config (AITER fmha uses it)).
//
// R4 theory: deepen the 8-phase pipeline. R3's vmcnt sync waited on
// half-tiles issued only 2 phases earlier (~350 cy) vs ~500-900 cy load
// latency -> stall at every sync (MfmaUtil 48%). Binding constraint was LDS
// region count (WAR blocks earlier staging). Fix: A triple-buffered
// (3x32 KiB) + B double-buffered (2x32 KiB) = 160 KiB (full CU LDS;
// occupancy already 1 block/CU at 128 KiB, so free). Uniform schedule
// stages exactly one half-tile per phase; every consumed half-tile is
// >=4 phases old at its vmcnt(8) sync; steady-state 8 loads in flight.
//
// Steady state iter i (tiles a=2i from Abuf ra / Bbuf0, b=2i+1 from Abuf rb / Bbuf1):
//   P1: rdA(ra,mi0-3)+rdB(B0,ni0-1), stage A(a+2).h0 -> Abuf ba, Q(0,0)
//   P2: rdB(B0,ni2-3),               stage A(a+2).h1 -> Abuf ba, Q(0,2)
//   P3: rdA(ra,mi4-7),               stage B(a+2).h0 -> Bbuf0,   Q(4,0)
//   P4:                              stage B(a+2).h1 -> Bbuf0,   Q(4,2), vmcnt(8)
//   P5: rdA(rb,mi0-3)+rdB(B1,ni0-1), stage A(b+2).h0 -> Abuf bb, Q(0,0)
//   P6: rdB(B1,ni2-3),               stage A(b+2).h1 -> Abuf bb, Q(0,2)
//   P7: rdA(rb,mi4-7),               stage B(b+2).h0 -> Bbuf1,   Q(4,0)
//   P8:                              stage B(b+2).h1 -> Bbuf1,   Q(4,2), vmcnt(8)
// with ra=(2i)%3, rb=(2i+1)%3, ba=(2i+2)%3, bb=ra. WAR ledger: each region's
// stage is issued >=1 barrier after that region's last ds_read completed
// (A(a+2) into ba: ba's tile a-1 last read prev-P7; B(a+2) into B0: last
// read P2; A(b+2) into bb=ra: ra last read P3; B(b+2) into B1: last read P6).
// RAW: tile a landed at prev-P8 vmcnt(8) (its 4 halves staged prev P1-P4);
// tile b landed at P4 vmcnt(8) (staged prev P5-P8). Cross-wave safety: each
// wave stages only its own rows and waits its own vmcnt BEFORE the
// s_barrier, so post-barrier the whole tile is visible.

static constexpr int Mdim = 8192;
static constexpr int Ndim = 4096;
static constexpr int Kdim = 4096;
static constexpr int BM = 256;
static constexpr int BN = 256;
static constexpr int BK = 64;
static constexpr int NT = Kdim / BK;  // 64 K-tiles

typedef __attribute__((ext_vector_type(8))) short short8;
typedef __attribute__((ext_vector_type(4))) float float4v;
typedef __attribute__((ext_vector_type(4))) float f32x4;
typedef __attribute__((ext_vector_type(4))) int int4v;
typedef __attribute__((ext_vector_type(8))) unsigned short ushort8;

__device__ __forceinline__ unsigned short f32_to_bf16(float f) {
  union { float f; uint32_t u; } c; c.f = f;
  uint32_t u = c.u;
  u += 0x7fffu + ((u >> 16) & 1u);   // round-to-nearest-even (no NaNs in data)
  return (unsigned short)(u >> 16);
}

// ---------------------------------------------------------------------------
// Mask element-width detection. numpy bool_ = 1 byte; int32/float32 promotion
// would zero byte positions ==1 (mod 4). 10% density over 1M positions ->
// ~105k hits for byte layout, exactly 0 for 4-byte layouts.
// ---------------------------------------------------------------------------
__global__ void detect_mask_kernel(const unsigned char* __restrict__ m, int* __restrict__ flag) {
  int found = 0;
  const int total = 1 << 20;  // scan first 4 MiB
  for (int p = blockIdx.x * blockDim.x + threadIdx.x; p < total;
       p += gridDim.x * blockDim.x)
    found |= (m[4 * p + 1] != 0);
  if (__any(found) && (threadIdx.x & 63) == 0) atomicOr(flag, 1);
}

// x fp32 -> bf16, 8 elements/thread (two 16B loads, one 16B store)
__global__ void cvt_x_kernel(const float* __restrict__ x, unsigned short* __restrict__ o) {
  long i = (blockIdx.x * (long)blockDim.x + threadIdx.x) * 8;
  float4v v0 = *(const float4v*)(x + i);
  float4v v1 = *(const float4v*)(x + i + 4);
  ushort8 r;
  r[0] = f32_to_bf16(v0[0]); r[1] = f32_to_bf16(v0[1]);
  r[2] = f32_to_bf16(v0[2]); r[3] = f32_to_bf16(v0[3]);
  r[4] = f32_to_bf16(v1[0]); r[5] = f32_to_bf16(v1[1]);
  r[6] = f32_to_bf16(v1[2]); r[7] = f32_to_bf16(v1[3]);
  *(ushort8*)(o + i) = r;
}

// W fp32 * mask -> bf16, 8 elements/thread; mask layout chosen by *flag
__global__ void cvt_w_kernel(const float* __restrict__ w, const unsigned char* __restrict__ mraw,
                             const int* __restrict__ flag, unsigned short* __restrict__ o) {
  long i = (blockIdx.x * (long)blockDim.x + threadIdx.x) * 8;
  float4v w0 = *(const float4v*)(w + i);
  float4v w1 = *(const float4v*)(w + i + 4);
  int m[8];
  if (*flag) {  // 1-byte elements
    unsigned long long mb = *(const unsigned long long*)(mraw + i);
#pragma unroll
    for (int j = 0; j < 8; ++j) m[j] = ((mb >> (8 * j)) & 0xffull) != 0;
  } else {      // 4-byte elements (int32 0/1 or float32 0.0/1.0 — both: nonzero word)
    int4v a = *(const int4v*)((const int*)mraw + i);
    int4v b = *(const int4v*)((const int*)mraw + i + 4);
#pragma unroll
    for (int j = 0; j < 4; ++j) { m[j] = a[j] != 0; m[4 + j] = b[j] != 0; }
  }
  ushort8 r;
  r[0] = f32_to_bf16(m[0] ? w0[0] : 0.0f);
  r[1] = f32_to_bf16(m[1] ? w0[1] : 0.0f);
  r[2] = f32_to_bf16(m[2] ? w0[2] : 0.0f);
  r[3] = f32_to_bf16(m[3] ? w0[3] : 0.0f);
  r[4] = f32_to_bf16(m[4] ? w1[0] : 0.0f);
  r[5] = f32_to_bf16(m[5] ? w1[1] : 0.0f);
  r[6] = f32_to_bf16(m[6] ? w1[2] : 0.0f);
  r[7] = f32_to_bf16(m[7] ? w1[3] : 0.0f);
  *(ushort8*)(o + i) = r;
}

// ---------------------------------------------------------------------------
// 8-phase 256x256 GEMM helpers
// ---------------------------------------------------------------------------

__device__ __forceinline__ void gload16(const unsigned short* g, char* l) {
  __builtin_amdgcn_global_load_lds((const __attribute__((address_space(1))) void*)g,
                                   (__attribute__((address_space(3))) void*)l, 16, 0, 0);
}

// Stage one 128x64 half-tile (region 16 KiB): 2x global_load_lds(16B)/thread.
// g0 = per-thread source addr (row r0, pre-swizzled col); second load row r0+8.
__device__ __forceinline__ void stage_half(const unsigned short* g0, char* region, int l0) {
  gload16(g0, region + l0);
  gload16(g0 + 8 * Kdim, region + l0 + 1024);
}

// A fragment loads: baseA already includes buffer + wm half.
// Read chunk = ((s<<2)|kg) ^ (row&7); row&7 == lane&7 for all our rows.
template <int MI0>
__device__ __forceinline__ void load_a(short8 (&a)[4][2], const char* baseA,
                                       int arow, int kg, int w7) {
#pragma unroll
  for (int mi = 0; mi < 4; ++mi) {
    const char* rowp = baseA + ((MI0 + mi) * 16 + arow) * 128;
#pragma unroll
    for (int s = 0; s < 2; ++s)
      a[mi][s] = *(const short8*)(rowp + (((s << 2) | kg) ^ w7) * 16);
  }
}

// B fragment loads: baseB already includes buffer + wnh half.
template <int NI0>
__device__ __forceinline__ void load_b(short8 (&b)[4][2], const char* baseB,
                                       int brow, int kg, int w7) {
#pragma unroll
  for (int ni = 0; ni < 2; ++ni) {
    const char* rowp = baseB + (brow + (NI0 + ni) * 16) * 128;
#pragma unroll
    for (int s = 0; s < 2; ++s)
      b[NI0 + ni][s] = *(const short8*)(rowp + (((s << 2) | kg) ^ w7) * 16);
  }
}

// One C-quadrant x K=64: 16 MFMA (4 mi x 2 ni x 2 k-halves)
template <int MIB, int NIB>
__device__ __forceinline__ void mfma_quad(f32x4 (&acc)[8][4], const short8 (&a)[4][2],
                                          const short8 (&b)[4][2]) {
#pragma unroll
  for (int s = 0; s < 2; ++s)
#pragma unroll
    for (int mi = 0; mi < 4; ++mi)
#pragma unroll
      for (int ni = 0; ni < 2; ++ni)
        acc[MIB + mi][NIB + ni] = __builtin_amdgcn_mfma_f32_16x16x32_bf16(
            a[mi][s], b[NIB + ni][s], acc[MIB + mi][NIB + ni], 0, 0, 0);
}

__device__ __forceinline__ void phase_pre() {
  __builtin_amdgcn_sched_barrier(0);
  __builtin_amdgcn_s_barrier();
  asm volatile("s_waitcnt lgkmcnt(0)" ::: "memory");
  __builtin_amdgcn_sched_barrier(0);
  __builtin_amdgcn_s_setprio(1);
}

__device__ __forceinline__ void phase_post() {
  __builtin_amdgcn_s_setprio(0);
  __builtin_amdgcn_sched_barrier(0);
  __builtin_amdgcn_s_barrier();
}

__device__ __forceinline__ void phase_post_vm() {
  __builtin_amdgcn_s_setprio(0);
  __builtin_amdgcn_sched_barrier(0);
  asm volatile("s_waitcnt vmcnt(8)" ::: "memory");  // counted: 4 half-tiles stay in flight
  __builtin_amdgcn_sched_barrier(0);
  __builtin_amdgcn_s_barrier();
}

// ---------------------------------------------------------------------------
// bf16 MFMA GEMM, B^T form: O[m][n] = sum_k X[m][k]*W[n][k].
// 512 threads = 8 waves (2 M x 4 N); per-wave 128x64 via 16x16x32 MFMA.
// A/B frag layout: m/n = lane&15, k = (lane>>4)*8 + i.
// C/D layout (m89-verified): col = lane&15, row = (lane>>4)*4 + reg.
// LDS 160 KiB: A = 3 tile-bufs x 2 halves x 16 KiB, B = 2 x 2 x 16 KiB.
// XOR chunk swizzle (chunk ^= row&7): pre-swizzled global source col +
// swizzled ds_read addr; gload_lds dest stays linear.
// ---------------------------------------------------------------------------
__global__ __launch_bounds__(512, 2) void gemm_bt_kernel(const unsigned short* __restrict__ X,
                                                         const unsigned short* __restrict__ W,
                                                         float* __restrict__ O) {
  __shared__ __align__(16) char lds[163840];
  char* sA = lds;            // [3 bufs][2 halves][16384]
  char* sB = lds + 98304;    // [2 bufs][2 halves][16384]

  const int tid = threadIdx.x;
  const int lane = tid & 63;
  const int wave = tid >> 6;
  const int wm = wave >> 2;        // 0..1 : M half (rows wm*128..+128)
  const int wn = wave & 3;         // 0..3 : N strip (cols wn*64..+64)
  const int wnh = wn >> 1;         // which B half this wave reads

  // T1: XCD-aware swizzle. 512 blocks, 8 XCDs -> 64 contiguous tiles per XCD.
  const int bid = blockIdx.x;
  const int id = (bid & 7) * 64 + (bid >> 3);
  const int tm = id >> 4;          // 0..31
  const int tn = id & 15;          // 0..15
  const int row0 = tm * BM;
  const int col0 = tn * BN;

  // staging per-thread constants
  const int r0 = wave * 16 + (lane >> 3);             // row within half (j=0)
  const int gcol = ((lane & 7) ^ (lane >> 3)) * 8;    // pre-swizzled source col
  const int l0 = wave * 2048 + lane * 16;             // linear LDS byte offset

  // per-thread global staging bases (advance by k elems per tile)
  const unsigned short* gA0 = X + (size_t)(row0 + r0) * Kdim + gcol;   // A rows 0-127
  const unsigned short* gA1 = gA0 + (size_t)128 * Kdim;                // A rows 128-255
  const unsigned short* gB0 = W + (size_t)(col0 + r0) * Kdim + gcol;   // B rows 0-127
  const unsigned short* gB1 = gB0 + (size_t)128 * Kdim;                // B rows 128-255

  // ds_read per-thread constants
  const int arow = lane & 15;
  const int kg = lane >> 4;        // 0..3
  const int w7 = lane & 7;         // == row&7 for every row we read
  const int brow = (wn & 1) * 64 + arow;

  // B read bases (fixed: even tiles buf0, odd tiles buf1)
  const char* pBe = sB + wnh * 16384;
  const char* pBo = sB + 32768 + wnh * 16384;

  f32x4 acc[8][4];
#pragma unroll
  for (int i = 0; i < 8; ++i)
#pragma unroll
    for (int j = 0; j < 4; ++j)
#pragma unroll
      for (int r = 0; r < 4; ++r) acc[i][j][r] = 0.f;

  short8 a[4][2], b[4][2];

  // Prologue: tile 0 -> Abuf0/Bbuf0, tile 1 -> Abuf1/Bbuf1 (16 loads/thread)
  stage_half(gA0,      sA + 0,     l0);
  stage_half(gA1,      sA + 16384, l0);
  stage_half(gB0,      sB + 0,     l0);
  stage_half(gB1,      sB + 16384, l0);
  stage_half(gA0 + BK, sA + 32768, l0);
  stage_half(gA1 + BK, sA + 49152, l0);
  stage_half(gB0 + BK, sB + 32768, l0);
  stage_half(gB1 + BK, sB + 49152, l0);
  asm volatile("s_waitcnt vmcnt(8)" ::: "memory");  // tile 0 landed; tile 1 in flight
  __builtin_amdgcn_sched_barrier(0);
  __builtin_amdgcn_s_barrier();

  int ra = 0;  // A buffer of tile 2*it; rb=(ra+1)%3 tile 2it+1; ba=(ra+2)%3; bb=ra
#pragma unroll 1
  for (int it = 0; it < NT / 2; ++it) {
    const int rb = (ra == 2) ? 0 : ra + 1;
    const int ba = (rb == 2) ? 0 : rb + 1;
    const int bb = ra;
    const int k2 = ((2 * it + 2) & (NT - 1)) * BK;  // wrapped on tail: staged, never read
    const int k3 = ((2 * it + 3) & (NT - 1)) * BK;
    const char* pAr0 = sA + (ra * 2 + wm) * 16384;
    const char* pAr1 = sA + (rb * 2 + wm) * 16384;
    char* pAs0 = sA + ba * 32768;
    char* pAs1 = sA + bb * 32768;

    // ================= tile 2*it (Abuf ra, Bbuf0) =================
    // P1
    load_a<0>(a, pAr0, arow, kg, w7);
    load_b<0>(b, pBe, brow, kg, w7);
    stage_half(gA0 + k2, pAs0, l0);              // A(t+2).h0 -> ba (free since prev P7)
    phase_pre(); mfma_quad<0, 0>(acc, a, b); phase_post();
    // P2
    load_b<2>(b, pBe, brow, kg, w7);
    stage_half(gA1 + k2, pAs0 + 16384, l0);      // A(t+2).h1
    phase_pre(); mfma_quad<0, 2>(acc, a, b); phase_post();
    // P3
    load_a<4>(a, pAr0, arow, kg, w7);
    stage_half(gB0 + k2, sB + 0, l0);            // B(t+2).h0 -> Bbuf0 (read done P2)
    phase_pre(); mfma_quad<4, 0>(acc, a, b); phase_post();
    // P4
    stage_half(gB1 + k2, sB + 16384, l0);        // B(t+2).h1
    phase_pre(); mfma_quad<4, 2>(acc, a, b); phase_post_vm();  // tile 2it+1 landed

    // ================= tile 2*it+1 (Abuf rb, Bbuf1) =================
    // P5
    load_a<0>(a, pAr1, arow, kg, w7);
    load_b<0>(b, pBo, brow, kg, w7);
    stage_half(gA0 + k3, pAs1, l0);              // A(t+3).h0 -> bb=ra (read done P3)
    phase_pre(); mfma_quad<0, 0>(acc, a, b); phase_post();
    // P6
    load_b<2>(b, pBo, brow, kg, w7);
    stage_half(gA1 + k3, pAs1 + 16384, l0);      // A(t+3).h1
    phase_pre(); mfma_quad<0, 2>(acc, a, b); phase_post();
    // P7
    load_a<4>(a, pAr1, arow, kg, w7);
    stage_half(gB0 + k3, sB + 32768, l0);        // B(t+3).h0 -> Bbuf1 (read done P6)
    phase_pre(); mfma_quad<4, 0>(acc, a, b); phase_post();
    // P8
    stage_half(gB1 + k3, sB + 49152, l0);        // B(t+3).h1
    phase_pre(); mfma_quad<4, 2>(acc, a, b); phase_post_vm();  // tile 2it+2 landed

    ra = ba;
  }

  // Epilogue: C/D row = (lane>>4)*4 + reg, col = lane&15
  const int orow0 = row0 + wm * 128 + kg * 4;
  const int ocol0 = col0 + wn * 64 + arow;
#pragma unroll
  for (int mi = 0; mi < 8; ++mi)
#pragma unroll
    for (int ni = 0; ni < 4; ++ni)
#pragma unroll
      for (int r = 0; r < 4; ++r)
        O[(size_t)(orow0 + mi * 16 + r) * Ndim + ocol0 + ni * 16] = acc[mi][ni][r];
}

// ---------------------------------------------------------------------------
// Fallback (only if ws too small for bf16 staging): fp32 LDS-tiled GEMM.
// ---------------------------------------------------------------------------
__global__ void gemm_fallback_kernel(const float* __restrict__ X, const float* __restrict__ Wt,
                                     const unsigned char* __restrict__ mraw,
                                     const int* __restrict__ flag, float* __restrict__ O) {
  __shared__ float sX[16][17];
  __shared__ float sW[16][17];
  const int tx = threadIdx.x & 15;
  const int ty = threadIdx.x >> 4;
  const long row = blockIdx.y * 16 + ty;
  const long colblock = blockIdx.x * 16;
  const int byteLayout = *flag;
  float acc = 0.f;
  for (int k0 = 0; k0 < Kdim; k0 += 16) {
    sX[ty][tx] = X[row * Kdim + k0 + tx];
    const long wi = (colblock + ty) * (long)Kdim + k0 + tx;
    const int mv = byteLayout ? (mraw[wi] != 0) : (((const int*)mraw)[wi] != 0);
    sW[ty][tx] = mv ? Wt[wi] : 0.f;
    __syncthreads();
#pragma unroll
    for (int k = 0; k < 16; ++k) acc += sX[ty][k] * sW[tx][k];
    __syncthreads();
  }
  O[row * Ndim + colblock + tx] = acc;
}

extern "C" void kernel_launch(void* const* d_in, const int* in_sizes, int n_in,
                              void* d_out, int out_size, void* d_ws, size_t ws_size,
                              hipStream_t stream) {
  const float* x = (const float*)d_in[0];               // [8192, 4096] fp32
  const float* w = (const float*)d_in[1];               // [4096, 4096] fp32
  const unsigned char* mask = (const unsigned char*)d_in[2];  // bool (layout detected)
  float* out = (float*)d_out;                           // [8192, 4096] fp32

  const size_t xb_off = 0;
  const size_t wb_off = (size_t)Mdim * Kdim * 2;             // 67,108,864
  const size_t flag_off = wb_off + (size_t)Ndim * Kdim * 2;  // 100,663,296
  const size_t needed = flag_off + 16;

  if (ws_size >= needed) {
    unsigned short* xb = (unsigned short*)((char*)d_ws + xb_off);
    unsigned short* wb = (unsigned short*)((char*)d_ws + wb_off);
    int* flag = (int*)((char*)d_ws + flag_off);

    hipMemsetAsync(flag, 0, sizeof(int), stream);
    detect_mask_kernel<<<64, 256, 0, stream>>>(mask, flag);
    cvt_x_kernel<<<(int)(((long)Mdim * Kdim / 8) / 256), 256, 0, stream>>>(x, xb);
    cvt_w_kernel<<<(int)(((long)Ndim * Kdim / 8) / 256), 256, 0, stream>>>(w, mask, flag, wb);
    gemm_bt_kernel<<<(Mdim / BM) * (Ndim / BN), 512, 0, stream>>>(xb, wb, out);
  } else {
    int* flag = (int*)d_ws;
    hipMemsetAsync(flag, 0, sizeof(int), stream);
    detect_mask_kernel<<<64, 256, 0, stream>>>(mask, flag);
    dim3 grid(Ndim / 16, Mdim / 16);
    gemm_fallback_kernel<<<grid, 256, 0, stream>>>(x, w, mask, flag, out);
  }
}

// Round 4
// 539.297 us; speedup vs baseline: 1.0046x; 1.0046x over previous
//
#include <hip/hip_runtime.h>
#include <stdint.h>

// SparseLinear: out[m][n] = sum_k x[m][k] * W[n][k] * mask[n][k]
// M = B*S = 8192, N = 4096, K = 4096, fp32 in/out, bf16-tolerance check.
//
// R6: de-pin the scheduler. R5 (4-deep vmcnt, 160K LDS) was an exact null vs
// R3 -> stall is NOT load latency. Phase budget: MFMA 155 cy vs measured
// ~316 cy/phase (m201 template: ~250). Gap traced to my additions over the
// verified template: sched_barrier(0) x4/phase + forced asm lgkmcnt(0)
// full-drain before MFMA. hipcc emits fine-grained lgkmcnt(N) per dependent
// MFMA on its own (m97/r109); pinning defeats it (m141: 874->510). Rule 18
// (sched_barrier after lgkm) applies to inline-asm ds_reads only; ours are
// compiler-visible loads. This round: phase helpers = exact m201 template
// {barrier; setprio(1)} / {setprio(0); [vmcnt(8)]; barrier}. Body unchanged.
//
// WAR ledger under fine-grained waits: each read's lgkm wait retires before
// its first consuming MFMA (same phase), hence before that phase's bottom
// barrier; all stages target regions last-consumed >=1 barrier earlier:
//   A(t+2) @P1/P2 -> ba: last consumed prev-P7   | B(t+2) @P3/P4 -> Bbuf0:
//   b01 consumed P1, b23 consumed P2             | A(t+3) @P5/P6 -> ra:
//   consumed P1/P3                               | B(t+3) @P7/P8 -> Bbuf1:
//   consumed P5/P6.  RAW: vmcnt(8)+barrier at P4/P8 before first reads of
//   the landed tile (P5/P1). Cross-wave: own-vmcnt before s_barrier.

static constexpr int Mdim = 8192;
static constexpr int Ndim = 4096;
static constexpr int Kdim = 4096;
static constexpr int BM = 256;
static constexpr int BN = 256;
static constexpr int BK = 64;
static constexpr int NT = Kdim / BK;  // 64 K-tiles

typedef __attribute__((ext_vector_type(8))) short short8;
typedef __attribute__((ext_vector_type(4))) float float4v;
typedef __attribute__((ext_vector_type(4))) float f32x4;
typedef __attribute__((ext_vector_type(4))) int int4v;
typedef __attribute__((ext_vector_type(8))) unsigned short ushort8;

__device__ __forceinline__ unsigned short f32_to_bf16(float f) {
  union { float f; uint32_t u; } c; c.f = f;
  uint32_t u = c.u;
  u += 0x7fffu + ((u >> 16) & 1u);   // round-to-nearest-even (no NaNs in data)
  return (unsigned short)(u >> 16);
}

// ---------------------------------------------------------------------------
// Mask element-width detection. numpy bool_ = 1 byte; int32/float32 promotion
// would zero byte positions ==1 (mod 4). 10% density over 1M positions ->
// ~105k hits for byte layout, exactly 0 for 4-byte layouts.
// ---------------------------------------------------------------------------
__global__ void detect_mask_kernel(const unsigned char* __restrict__ m, int* __restrict__ flag) {
  int found = 0;
  const int total = 1 << 20;  // scan first 4 MiB
  for (int p = blockIdx.x * blockDim.x + threadIdx.x; p < total;
       p += gridDim.x * blockDim.x)
    found |= (m[4 * p + 1] != 0);
  if (__any(found) && (threadIdx.x & 63) == 0) atomicOr(flag, 1);
}

// x fp32 -> bf16, 8 elements/thread (two 16B loads, one 16B store)
__global__ void cvt_x_kernel(const float* __restrict__ x, unsigned short* __restrict__ o) {
  long i = (blockIdx.x * (long)blockDim.x + threadIdx.x) * 8;
  float4v v0 = *(const float4v*)(x + i);
  float4v v1 = *(const float4v*)(x + i + 4);
  ushort8 r;
  r[0] = f32_to_bf16(v0[0]); r[1] = f32_to_bf16(v0[1]);
  r[2] = f32_to_bf16(v0[2]); r[3] = f32_to_bf16(v0[3]);
  r[4] = f32_to_bf16(v1[0]); r[5] = f32_to_bf16(v1[1]);
  r[6] = f32_to_bf16(v1[2]); r[7] = f32_to_bf16(v1[3]);
  *(ushort8*)(o + i) = r;
}

// W fp32 * mask -> bf16, 8 elements/thread; mask layout chosen by *flag
__global__ void cvt_w_kernel(const float* __restrict__ w, const unsigned char* __restrict__ mraw,
                             const int* __restrict__ flag, unsigned short* __restrict__ o) {
  long i = (blockIdx.x * (long)blockDim.x + threadIdx.x) * 8;
  float4v w0 = *(const float4v*)(w + i);
  float4v w1 = *(const float4v*)(w + i + 4);
  int m[8];
  if (*flag) {  // 1-byte elements
    unsigned long long mb = *(const unsigned long long*)(mraw + i);
#pragma unroll
    for (int j = 0; j < 8; ++j) m[j] = ((mb >> (8 * j)) & 0xffull) != 0;
  } else {      // 4-byte elements (int32 0/1 or float32 0.0/1.0 — both: nonzero word)
    int4v a = *(const int4v*)((const int*)mraw + i);
    int4v b = *(const int4v*)((const int*)mraw + i + 4);
#pragma unroll
    for (int j = 0; j < 4; ++j) { m[j] = a[j] != 0; m[4 + j] = b[j] != 0; }
  }
  ushort8 r;
  r[0] = f32_to_bf16(m[0] ? w0[0] : 0.0f);
  r[1] = f32_to_bf16(m[1] ? w0[1] : 0.0f);
  r[2] = f32_to_bf16(m[2] ? w0[2] : 0.0f);
  r[3] = f32_to_bf16(m[3] ? w0[3] : 0.0f);
  r[4] = f32_to_bf16(m[4] ? w1[0] : 0.0f);
  r[5] = f32_to_bf16(m[5] ? w1[1] : 0.0f);
  r[6] = f32_to_bf16(m[6] ? w1[2] : 0.0f);
  r[7] = f32_to_bf16(m[7] ? w1[3] : 0.0f);
  *(ushort8*)(o + i) = r;
}

// ---------------------------------------------------------------------------
// 8-phase 256x256 GEMM helpers
// ---------------------------------------------------------------------------

__device__ __forceinline__ void gload16(const unsigned short* g, char* l) {
  __builtin_amdgcn_global_load_lds((const __attribute__((address_space(1))) void*)g,
                                   (__attribute__((address_space(3))) void*)l, 16, 0, 0);
}

// Stage one 128x64 half-tile (region 16 KiB): 2x global_load_lds(16B)/thread.
// g0 = per-thread source addr (row r0, pre-swizzled col); second load row r0+8.
__device__ __forceinline__ void stage_half(const unsigned short* g0, char* region, int l0) {
  gload16(g0, region + l0);
  gload16(g0 + 8 * Kdim, region + l0 + 1024);
}

// A fragment loads: baseA already includes buffer + wm half.
// Read chunk = ((s<<2)|kg) ^ (row&7); row&7 == lane&7 for all our rows.
template <int MI0>
__device__ __forceinline__ void load_a(short8 (&a)[4][2], const char* baseA,
                                       int arow, int kg, int w7) {
#pragma unroll
  for (int mi = 0; mi < 4; ++mi) {
    const char* rowp = baseA + ((MI0 + mi) * 16 + arow) * 128;
#pragma unroll
    for (int s = 0; s < 2; ++s)
      a[mi][s] = *(const short8*)(rowp + (((s << 2) | kg) ^ w7) * 16);
  }
}

// B fragment loads: baseB already includes buffer + wnh half.
template <int NI0>
__device__ __forceinline__ void load_b(short8 (&b)[4][2], const char* baseB,
                                       int brow, int kg, int w7) {
#pragma unroll
  for (int ni = 0; ni < 2; ++ni) {
    const char* rowp = baseB + (brow + (NI0 + ni) * 16) * 128;
#pragma unroll
    for (int s = 0; s < 2; ++s)
      b[NI0 + ni][s] = *(const short8*)(rowp + (((s << 2) | kg) ^ w7) * 16);
  }
}

// One C-quadrant x K=64: 16 MFMA (4 mi x 2 ni x 2 k-halves)
template <int MIB, int NIB>
__device__ __forceinline__ void mfma_quad(f32x4 (&acc)[8][4], const short8 (&a)[4][2],
                                          const short8 (&b)[4][2]) {
#pragma unroll
  for (int s = 0; s < 2; ++s)
#pragma unroll
    for (int mi = 0; mi < 4; ++mi)
#pragma unroll
      for (int ni = 0; ni < 2; ++ni)
        acc[MIB + mi][NIB + ni] = __builtin_amdgcn_mfma_f32_16x16x32_bf16(
            a[mi][s], b[NIB + ni][s], acc[MIB + mi][NIB + ni], 0, 0, 0);
}

// m201-template phase brackets: no sched_barrier pins, no forced lgkm drain.
// Compiler emits fine-grained lgkmcnt(N) for each ds_read->MFMA dependency.
__device__ __forceinline__ void phase_pre() {
  __builtin_amdgcn_s_barrier();
  __builtin_amdgcn_s_setprio(1);
}

__device__ __forceinline__ void phase_post() {
  __builtin_amdgcn_s_setprio(0);
  __builtin_amdgcn_s_barrier();
}

__device__ __forceinline__ void phase_post_vm() {
  __builtin_amdgcn_s_setprio(0);
  asm volatile("s_waitcnt vmcnt(8)" ::: "memory");  // counted: 4 half-tiles in flight
  __builtin_amdgcn_s_barrier();
}

// ---------------------------------------------------------------------------
// bf16 MFMA GEMM, B^T form: O[m][n] = sum_k X[m][k]*W[n][k].
// 512 threads = 8 waves (2 M x 4 N); per-wave 128x64 via 16x16x32 MFMA.
// A/B frag layout: m/n = lane&15, k = (lane>>4)*8 + i.
// C/D layout (m89-verified): col = lane&15, row = (lane>>4)*4 + reg.
// LDS 160 KiB: A = 3 tile-bufs x 2 halves x 16 KiB, B = 2 x 2 x 16 KiB.
// XOR chunk swizzle (chunk ^= row&7): pre-swizzled global source col +
// swizzled ds_read addr; gload_lds dest stays linear.
// ---------------------------------------------------------------------------
__global__ __launch_bounds__(512, 2) void gemm_bt_kernel(const unsigned short* __restrict__ X,
                                                         const unsigned short* __restrict__ W,
                                                         float* __restrict__ O) {
  __shared__ __align__(16) char lds[163840];
  char* sA = lds;            // [3 bufs][2 halves][16384]
  char* sB = lds + 98304;    // [2 bufs][2 halves][16384]

  const int tid = threadIdx.x;
  const int lane = tid & 63;
  const int wave = tid >> 6;
  const int wm = wave >> 2;        // 0..1 : M half (rows wm*128..+128)
  const int wn = wave & 3;         // 0..3 : N strip (cols wn*64..+64)
  const int wnh = wn >> 1;         // which B half this wave reads

  // T1: XCD-aware swizzle. 512 blocks, 8 XCDs -> 64 contiguous tiles per XCD.
  const int bid = blockIdx.x;
  const int id = (bid & 7) * 64 + (bid >> 3);
  const int tm = id >> 4;          // 0..31
  const int tn = id & 15;          // 0..15
  const int row0 = tm * BM;
  const int col0 = tn * BN;

  // staging per-thread constants
  const int r0 = wave * 16 + (lane >> 3);             // row within half (j=0)
  const int gcol = ((lane & 7) ^ (lane >> 3)) * 8;    // pre-swizzled source col
  const int l0 = wave * 2048 + lane * 16;             // linear LDS byte offset

  // per-thread global staging bases (advance by k elems per tile)
  const unsigned short* gA0 = X + (size_t)(row0 + r0) * Kdim + gcol;   // A rows 0-127
  const unsigned short* gA1 = gA0 + (size_t)128 * Kdim;                // A rows 128-255
  const unsigned short* gB0 = W + (size_t)(col0 + r0) * Kdim + gcol;   // B rows 0-127
  const unsigned short* gB1 = gB0 + (size_t)128 * Kdim;                // B rows 128-255

  // ds_read per-thread constants
  const int arow = lane & 15;
  const int kg = lane >> 4;        // 0..3
  const int w7 = lane & 7;         // == row&7 for every row we read
  const int brow = (wn & 1) * 64 + arow;

  // B read bases (fixed: even tiles buf0, odd tiles buf1)
  const char* pBe = sB + wnh * 16384;
  const char* pBo = sB + 32768 + wnh * 16384;

  f32x4 acc[8][4];
#pragma unroll
  for (int i = 0; i < 8; ++i)
#pragma unroll
    for (int j = 0; j < 4; ++j)
#pragma unroll
      for (int r = 0; r < 4; ++r) acc[i][j][r] = 0.f;

  short8 a[4][2], b[4][2];

  // Prologue: tile 0 -> Abuf0/Bbuf0, tile 1 -> Abuf1/Bbuf1 (16 loads/thread)
  stage_half(gA0,      sA + 0,     l0);
  stage_half(gA1,      sA + 16384, l0);
  stage_half(gB0,      sB + 0,     l0);
  stage_half(gB1,      sB + 16384, l0);
  stage_half(gA0 + BK, sA + 32768, l0);
  stage_half(gA1 + BK, sA + 49152, l0);
  stage_half(gB0 + BK, sB + 32768, l0);
  stage_half(gB1 + BK, sB + 49152, l0);
  asm volatile("s_waitcnt vmcnt(8)" ::: "memory");  // tile 0 landed; tile 1 in flight
  __builtin_amdgcn_s_barrier();

  int ra = 0;  // A buffer of tile 2*it; rb=(ra+1)%3 tile 2it+1; ba=(ra+2)%3; bb=ra
#pragma unroll 1
  for (int it = 0; it < NT / 2; ++it) {
    const int rb = (ra == 2) ? 0 : ra + 1;
    const int ba = (rb == 2) ? 0 : rb + 1;
    const int bb = ra;
    const int k2 = ((2 * it + 2) & (NT - 1)) * BK;  // wrapped on tail: staged, never read
    const int k3 = ((2 * it + 3) & (NT - 1)) * BK;
    const char* pAr0 = sA + (ra * 2 + wm) * 16384;
    const char* pAr1 = sA + (rb * 2 + wm) * 16384;
    char* pAs0 = sA + ba * 32768;
    char* pAs1 = sA + bb * 32768;

    // ================= tile 2*it (Abuf ra, Bbuf0) =================
    // P1
    load_a<0>(a, pAr0, arow, kg, w7);
    load_b<0>(b, pBe, brow, kg, w7);
    stage_half(gA0 + k2, pAs0, l0);              // A(t+2).h0 -> ba (free since prev P7)
    phase_pre(); mfma_quad<0, 0>(acc, a, b); phase_post();
    // P2
    load_b<2>(b, pBe, brow, kg, w7);
    stage_half(gA1 + k2, pAs0 + 16384, l0);      // A(t+2).h1
    phase_pre(); mfma_quad<0, 2>(acc, a, b); phase_post();
    // P3
    load_a<4>(a, pAr0, arow, kg, w7);
    stage_half(gB0 + k2, sB + 0, l0);            // B(t+2).h0 -> Bbuf0 (read done P2)
    phase_pre(); mfma_quad<4, 0>(acc, a, b); phase_post();
    // P4
    stage_half(gB1 + k2, sB + 16384, l0);        // B(t+2).h1
    phase_pre(); mfma_quad<4, 2>(acc, a, b); phase_post_vm();  // tile 2it+1 landed

    // ================= tile 2*it+1 (Abuf rb, Bbuf1) =================
    // P5
    load_a<0>(a, pAr1, arow, kg, w7);
    load_b<0>(b, pBo, brow, kg, w7);
    stage_half(gA0 + k3, pAs1, l0);              // A(t+3).h0 -> bb=ra (read done P3)
    phase_pre(); mfma_quad<0, 0>(acc, a, b); phase_post();
    // P6
    load_b<2>(b, pBo, brow, kg, w7);
    stage_half(gA1 + k3, pAs1 + 16384, l0);      // A(t+3).h1
    phase_pre(); mfma_quad<0, 2>(acc, a, b); phase_post();
    // P7
    load_a<4>(a, pAr1, arow, kg, w7);
    stage_half(gB0 + k3, sB + 32768, l0);        // B(t+3).h0 -> Bbuf1 (read done P6)
    phase_pre(); mfma_quad<4, 0>(acc, a, b); phase_post();
    // P8
    stage_half(gB1 + k3, sB + 49152, l0);        // B(t+3).h1
    phase_pre(); mfma_quad<4, 2>(acc, a, b); phase_post_vm();  // tile 2it+2 landed

    ra = ba;
  }

  // Epilogue: C/D row = (lane>>4)*4 + reg, col = lane&15
  const int orow0 = row0 + wm * 128 + kg * 4;
  const int ocol0 = col0 + wn * 64 + arow;
#pragma unroll
  for (int mi = 0; mi < 8; ++mi)
#pragma unroll
    for (int ni = 0; ni < 4; ++ni)
#pragma unroll
      for (int r = 0; r < 4; ++r)
        O[(size_t)(orow0 + mi * 16 + r) * Ndim + ocol0 + ni * 16] = acc[mi][ni][r];
}

// ---------------------------------------------------------------------------
// Fallback (only if ws too small for bf16 staging): fp32 LDS-tiled GEMM.
// ---------------------------------------------------------------------------
__global__ void gemm_fallback_kernel(const float* __restrict__ X, const float* __restrict__ Wt,
                                     const unsigned char* __restrict__ mraw,
                                     const int* __restrict__ flag, float* __restrict__ O) {
  __shared__ float sX[16][17];
  __shared__ float sW[16][17];
  const int tx = threadIdx.x & 15;
  const int ty = threadIdx.x >> 4;
  const long row = blockIdx.y * 16 + ty;
  const long colblock = blockIdx.x * 16;
  const int byteLayout = *flag;
  float acc = 0.f;
  for (int k0 = 0; k0 < Kdim; k0 += 16) {
    sX[ty][tx] = X[row * Kdim + k0 + tx];
    const long wi = (colblock + ty) * (long)Kdim + k0 + tx;
    const int mv = byteLayout ? (mraw[wi] != 0) : (((const int*)mraw)[wi] != 0);
    sW[ty][tx] = mv ? Wt[wi] : 0.f;
    __syncthreads();
#pragma unroll
    for (int k = 0; k < 16; ++k) acc += sX[ty][k] * sW[tx][k];
    __syncthreads();
  }
  O[row * Ndim + colblock + tx] = acc;
}

extern "C" void kernel_launch(void* const* d_in, const int* in_sizes, int n_in,
                              void* d_out, int out_size, void* d_ws, size_t ws_size,
                              hipStream_t stream) {
  const float* x = (const float*)d_in[0];               // [8192, 4096] fp32
  const float* w = (const float*)d_in[1];               // [4096, 4096] fp32
  const unsigned char* mask = (const unsigned char*)d_in[2];  // bool (layout detected)
  float* out = (float*)d_out;                           // [8192, 4096] fp32

  const size_t xb_off = 0;
  const size_t wb_off = (size_t)Mdim * Kdim * 2;             // 67,108,864
  const size_t flag_off = wb_off + (size_t)Ndim * Kdim * 2;  // 100,663,296
  const size_t needed = flag_off + 16;

  if (ws_size >= needed) {
    unsigned short* xb = (unsigned short*)((char*)d_ws + xb_off);
    unsigned short* wb = (unsigned short*)((char*)d_ws + wb_off);
    int* flag = (int*)((char*)d_ws + flag_off);

    hipMemsetAsync(flag, 0, sizeof(int), stream);
    detect_mask_kernel<<<64, 256, 0, stream>>>(mask, flag);
    cvt_x_kernel<<<(int)(((long)Mdim * Kdim / 8) / 256), 256, 0, stream>>>(x, xb);
    cvt_w_kernel<<<(int)(((long)Ndim * Kdim / 8) / 256), 256, 0, stream>>>(w, mask, flag, wb);
    gemm_bt_kernel<<<(Mdim / BM) * (Ndim / BN), 512, 0, stream>>>(xb, wb, out);
  } else {
    int* flag = (int*)d_ws;
    hipMemsetAsync(flag, 0, sizeof(int), stream);
    detect_mask_kernel<<<64, 256, 0, stream>>>(mask, flag);
    dim3 grid(Ndim / 16, Mdim / 16);
    gemm_fallback_kernel<<<grid, 256, 0, stream>>>(x, w, mask, flag, out);
  }
}